// Round 1
// baseline (684.296 us; speedup 1.0000x reference)
//
#include <hip/hip_runtime.h>

#define NN 100000
#define NE 1600000
#define ENT (NE + NN)   // edges + self loops

// ---------------- CSR build ----------------

__global__ void probe_kernel(const unsigned* __restrict__ edges, int* __restrict__ flag) {
    if (threadIdx.x == 0 && blockIdx.x == 0) {
        int is64 = 1;
        for (int i = 1; i < 64; i += 2)
            if (edges[i] != 0u) { is64 = 0; break; }
        *flag = is64;
    }
}

__global__ void convert_kernel(const void* __restrict__ edges, const int* __restrict__ flag,
                               int* __restrict__ out) {
    int i = blockIdx.x * blockDim.x + threadIdx.x;
    if (i >= 2 * NE) return;
    if (*flag) out[i] = (int)((const long long*)edges)[i];
    else       out[i] = ((const int*)edges)[i];
}

__global__ void count_kernel(const int* __restrict__ e32, int* __restrict__ cnt) {
    int i = blockIdx.x * blockDim.x + threadIdx.x;
    if (i < NE) atomicAdd(&cnt[e32[NE + i]], 1);
}

__global__ void dinv_kernel(const int* __restrict__ cnt, float* __restrict__ dinv) {
    int i = blockIdx.x * blockDim.x + threadIdx.x;
    if (i < NN) dinv[i] = rsqrtf((float)(cnt[i] + 1));  // +1 self loop, always > 0
}

__global__ __launch_bounds__(1024) void scan_local(const int* __restrict__ cnt,
                                                   int* __restrict__ rowoff,
                                                   int* __restrict__ part) {
    __shared__ int s[1024];
    int t = threadIdx.x;
    int i = blockIdx.x * 1024 + t;
    int v = (i < NN) ? cnt[i] + 1 : 0;
    s[t] = v;
    __syncthreads();
    for (int off = 1; off < 1024; off <<= 1) {
        int a = (t >= off) ? s[t - off] : 0;
        __syncthreads();
        s[t] += a;
        __syncthreads();
    }
    if (i < NN) rowoff[i] = s[t] - v;     // exclusive (local)
    if (t == 1023) part[blockIdx.x] = s[t];
}

__global__ void scan_part(int* __restrict__ part, int nb) {
    __shared__ int s[128];
    int t = threadIdx.x;
    int v = (t < nb) ? part[t] : 0;
    s[t] = v;
    __syncthreads();
    for (int off = 1; off < 128; off <<= 1) {
        int a = (t >= off) ? s[t - off] : 0;
        __syncthreads();
        s[t] += a;
        __syncthreads();
    }
    if (t < nb) part[t] = s[t] - v;       // exclusive
}

__global__ void scan_add(int* __restrict__ rowoff, const int* __restrict__ part) {
    int i = blockIdx.x * blockDim.x + threadIdx.x;
    if (i < NN) rowoff[i] += part[i >> 10];
    if (i == 0) rowoff[NN] = ENT;
}

__global__ void fill_kernel(const int* __restrict__ e32, const float* __restrict__ dinv,
                            const int* __restrict__ rowoff, int* __restrict__ cursor,
                            int* __restrict__ col, float* __restrict__ val) {
    int i = blockIdx.x * blockDim.x + threadIdx.x;
    if (i >= ENT) return;
    int s, j;
    if (i < NE) { s = e32[i]; j = e32[NE + i]; }
    else        { s = i - NE; j = s; }
    int p = rowoff[j] + atomicAdd(&cursor[j], 1);
    col[p] = s;
    val[p] = dinv[s] * dinv[j];
}

// ---------------- propagate: one wave per node, gather over in-edges ----------------

template<int VEC>   // VEC floats per lane; F = 64*VEC
__global__ __launch_bounds__(256) void spmm_kernel(const int* __restrict__ rowoff,
                                                   const int* __restrict__ col,
                                                   const float* __restrict__ val,
                                                   const float* __restrict__ H,
                                                   float* __restrict__ O) {
    constexpr int F = 64 * VEC;
    int w = (int)((blockIdx.x * (unsigned)blockDim.x + threadIdx.x) >> 6);
    if (w >= NN) return;
    int lane = threadIdx.x & 63;
    int s = rowoff[w], e = rowoff[w + 1];
    float a0 = 0.f, a1 = 0.f;
    const float* base = H + (size_t)lane * VEC;
    int p = s;
    for (; p + 2 <= e; p += 2) {
        int   c0 = col[p],  c1 = col[p + 1];
        float v0 = val[p],  v1 = val[p + 1];
        if constexpr (VEC == 2) {
            float2 h0 = *(const float2*)(base + (size_t)c0 * F);
            float2 h1 = *(const float2*)(base + (size_t)c1 * F);
            a0 += v0 * h0.x; a1 += v0 * h0.y;
            a0 += v1 * h1.x; a1 += v1 * h1.y;
        } else {
            a0 += v0 * base[(size_t)c0 * F];
            a0 += v1 * base[(size_t)c1 * F];
        }
    }
    if (p < e) {
        int c0 = col[p]; float v0 = val[p];
        if constexpr (VEC == 2) {
            float2 h0 = *(const float2*)(base + (size_t)c0 * F);
            a0 += v0 * h0.x; a1 += v0 * h0.y;
        } else {
            a0 += v0 * base[(size_t)c0 * F];
        }
    }
    float* o = O + (size_t)w * F + (size_t)lane * VEC;
    if constexpr (VEC == 2) { o[0] = a0; o[1] = a1; }
    else                    { o[0] = a0; }
}

// ---------------- fp32 GEMM: Y[M,N] = X[M,128] @ W[N,128]^T ----------------

template<int N>   // N = 128 or 64
__global__ __launch_bounds__(256) void gemm_xwt(const float* __restrict__ X,
                                                const float* __restrict__ W,
                                                float* __restrict__ Y, int M) {
    constexpr int K = 128, BM = 64, BK = 32;
    constexpr int TM = 4, TN = N / 16;
    __shared__ float Xs[BK][BM + 4];    // padded, rows 16B-aligned
    __shared__ float Ws[BK][N + 4];
    int t  = threadIdx.x;
    int m0 = blockIdx.x * BM;
    int r0 = (t >> 4) * TM;
    int c0 = (t & 15) * TN;
    float acc[TM][TN] = {};
    for (int k0 = 0; k0 < K; k0 += BK) {
        #pragma unroll
        for (int i = 0; i < 2; ++i) {            // X tile: 512 float4
            int f  = t + i * 256;
            int m  = f >> 3;
            int kq = (f & 7) << 2;
            int gm = m0 + m; if (gm >= M) gm = M - 1;
            float4 v = *(const float4*)&X[(size_t)gm * K + k0 + kq];
            Xs[kq + 0][m] = v.x; Xs[kq + 1][m] = v.y;
            Xs[kq + 2][m] = v.z; Xs[kq + 3][m] = v.w;
        }
        #pragma unroll
        for (int i = 0; i < N / 32; ++i) {       // W tile: N*8 float4
            int f  = t + i * 256;
            int n  = f >> 3;
            int kq = (f & 7) << 2;
            float4 v = *(const float4*)&W[(size_t)n * K + k0 + kq];
            Ws[kq + 0][n] = v.x; Ws[kq + 1][n] = v.y;
            Ws[kq + 2][n] = v.z; Ws[kq + 3][n] = v.w;
        }
        __syncthreads();
        #pragma unroll
        for (int k = 0; k < BK; ++k) {
            float4 xv = *(const float4*)&Xs[k][r0];
            float xf[TM] = {xv.x, xv.y, xv.z, xv.w};
            float wf[TN];
            #pragma unroll
            for (int j = 0; j < TN; j += 4) {
                float4 wv = *(const float4*)&Ws[k][c0 + j];
                wf[j] = wv.x; wf[j + 1] = wv.y; wf[j + 2] = wv.z; wf[j + 3] = wv.w;
            }
            #pragma unroll
            for (int i = 0; i < TM; ++i)
                #pragma unroll
                for (int j = 0; j < TN; ++j)
                    acc[i][j] += xf[i] * wf[j];
        }
        __syncthreads();
    }
    #pragma unroll
    for (int i = 0; i < TM; ++i) {
        int gm = m0 + r0 + i;
        if (gm < M) {
            #pragma unroll
            for (int j = 0; j < TN; j += 4) {
                float4 v = {acc[i][j], acc[i][j + 1], acc[i][j + 2], acc[i][j + 3]};
                *(float4*)&Y[(size_t)gm * N + c0 + j] = v;
            }
        }
    }
}

// ---------------- launch ----------------

extern "C" void kernel_launch(void* const* d_in, const int* in_sizes, int n_in,
                              void* d_out, int out_size, void* d_ws, size_t ws_size,
                              hipStream_t stream) {
    const float* x     = (const float*)d_in[0];
    const void*  edges = d_in[1];
    const float* W1    = (const float*)d_in[2];
    const float* W2    = (const float*)d_in[3];
    float* out = (float*)d_out;

    char* ws = (char*)d_ws;
    size_t off = 0;
    auto take = [&](size_t bytes) -> char* {
        char* p = ws + off;
        off = (off + bytes + 255) & ~(size_t)255;
        return p;
    };
    int*   flag   = (int*)take(4);
    int*   e32    = (int*)take((size_t)2 * NE * 4);
    int*   cnt    = (int*)take((size_t)NN * 4);        // reused as fill cursor
    float* dinv   = (float*)take((size_t)NN * 4);
    int*   rowoff = (int*)take((size_t)(NN + 1) * 4);
    int*   part   = (int*)take(1024 * 4);
    int*   colA   = (int*)take((size_t)ENT * 4);
    float* valA   = (float*)take((size_t)ENT * 4);
    float* h      = (float*)take((size_t)NN * 128 * 4);
    float* y      = (float*)take((size_t)NN * 128 * 4);
    if (off > ws_size) return;   // workspace too small: fail cleanly

    // --- build normalized CSR (by dst) ---
    hipMemsetAsync(cnt, 0, (size_t)NN * 4, stream);
    probe_kernel<<<1, 64, 0, stream>>>((const unsigned*)edges, flag);
    convert_kernel<<<(2 * NE + 255) / 256, 256, 0, stream>>>(edges, flag, e32);
    count_kernel<<<(NE + 255) / 256, 256, 0, stream>>>(e32, cnt);
    dinv_kernel<<<(NN + 255) / 256, 256, 0, stream>>>(cnt, dinv);
    int nb = (NN + 1023) / 1024;   // 98
    scan_local<<<nb, 1024, 0, stream>>>(cnt, rowoff, part);
    scan_part<<<1, 128, 0, stream>>>(part, nb);
    scan_add<<<(NN + 255) / 256, 256, 0, stream>>>(rowoff, part);
    hipMemsetAsync(cnt, 0, (size_t)NN * 4, stream);
    fill_kernel<<<(ENT + 255) / 256, 256, 0, stream>>>(e32, dinv, rowoff, cnt, colA, valA);

    // --- 3 layers: GEMM then propagate ---
    const int GB = (NN + 63) / 64;          // 1563
    const int PB = (NN * 64 + 255) / 256;   // 25000 (one wave per node)

    gemm_xwt<128><<<GB, 256, 0, stream>>>(x, W1, h, NN);
    spmm_kernel<2><<<PB, 256, 0, stream>>>(rowoff, colA, valA, h, y);

    gemm_xwt<128><<<GB, 256, 0, stream>>>(y, W1, h, NN);
    spmm_kernel<2><<<PB, 256, 0, stream>>>(rowoff, colA, valA, h, y);

    gemm_xwt<64><<<GB, 256, 0, stream>>>(y, W2, h, NN);
    spmm_kernel<1><<<PB, 256, 0, stream>>>(rowoff, colA, valA, h, out);
}

// Round 2
// 600.381 us; speedup vs baseline: 1.1398x; 1.1398x over previous
//
#include <hip/hip_runtime.h>

#define NN 100000
#define NE 1600000
#define ENT (NE + NN)   // edges + self loops

// ---------------- CSR build ----------------

__global__ void probe_kernel(const unsigned* __restrict__ edges, int* __restrict__ flag) {
    if (threadIdx.x == 0 && blockIdx.x == 0) {
        int is64 = 1;
        for (int i = 1; i < 64; i += 2)
            if (edges[i] != 0u) { is64 = 0; break; }
        *flag = is64;
    }
}

// convert to int32 AND count in-degree (dst half) in one pass
__global__ void convert_kernel(const void* __restrict__ edges, const int* __restrict__ flag,
                               int* __restrict__ out, int* __restrict__ cnt) {
    int i = blockIdx.x * blockDim.x + threadIdx.x;
    if (i >= 2 * NE) return;
    int v;
    if (*flag) v = (int)((const long long*)edges)[i];
    else       v = ((const int*)edges)[i];
    out[i] = v;
    if (i >= NE) atomicAdd(&cnt[v], 1);
}

__global__ void dinv_kernel(const int* __restrict__ cnt, float* __restrict__ dinv) {
    int i = blockIdx.x * blockDim.x + threadIdx.x;
    if (i < NN) dinv[i] = rsqrtf((float)(cnt[i] + 1));  // +1 self loop, always > 0
}

__global__ __launch_bounds__(1024) void scan_local(const int* __restrict__ cnt,
                                                   int* __restrict__ rowoff,
                                                   int* __restrict__ part) {
    __shared__ int s[1024];
    int t = threadIdx.x;
    int i = blockIdx.x * 1024 + t;
    int v = (i < NN) ? cnt[i] + 1 : 0;
    s[t] = v;
    __syncthreads();
    for (int off = 1; off < 1024; off <<= 1) {
        int a = (t >= off) ? s[t - off] : 0;
        __syncthreads();
        s[t] += a;
        __syncthreads();
    }
    if (i < NN) rowoff[i] = s[t] - v;     // exclusive (local)
    if (t == 1023) part[blockIdx.x] = s[t];
}

__global__ void scan_part(int* __restrict__ part, int nb) {
    __shared__ int s[128];
    int t = threadIdx.x;
    int v = (t < nb) ? part[t] : 0;
    s[t] = v;
    __syncthreads();
    for (int off = 1; off < 128; off <<= 1) {
        int a = (t >= off) ? s[t - off] : 0;
        __syncthreads();
        s[t] += a;
        __syncthreads();
    }
    if (t < nb) part[t] = s[t] - v;       // exclusive
}

// finalize rowoff AND initialize the fill cursor to the same offsets
__global__ void scan_add(int* __restrict__ rowoff, int* __restrict__ cursor,
                         const int* __restrict__ part) {
    int i = blockIdx.x * blockDim.x + threadIdx.x;
    if (i < NN) {
        int v = rowoff[i] + part[i >> 10];
        rowoff[i] = v;
        cursor[i] = v;
    }
    if (i == 0) rowoff[NN] = ENT;
}

// one packed 8B scatter per edge: (src, norm-bits)
__global__ void fill_kernel(const int* __restrict__ e32, const float* __restrict__ dinv,
                            int* __restrict__ cursor, int2* __restrict__ edge) {
    int i = blockIdx.x * blockDim.x + threadIdx.x;
    if (i >= ENT) return;
    int s, j;
    if (i < NE) { s = e32[i]; j = e32[NE + i]; }
    else        { s = i - NE; j = s; }
    int p = atomicAdd(&cursor[j], 1);
    float v = dinv[s] * dinv[j];
    edge[p] = make_int2(s, __float_as_int(v));
}

// ---------------- propagate: one wave per node, gather over in-edges ----------------

template<int VEC>   // VEC floats per lane; F = 64*VEC
__global__ __launch_bounds__(256) void spmm_kernel(const int* __restrict__ rowoff,
                                                   const int2* __restrict__ edge,
                                                   const float* __restrict__ H,
                                                   float* __restrict__ O) {
    constexpr int F = 64 * VEC;
    int w = (int)((blockIdx.x * (unsigned)blockDim.x + threadIdx.x) >> 6);
    if (w >= NN) return;
    int lane = threadIdx.x & 63;
    int s = rowoff[w], e = rowoff[w + 1];
    float a0 = 0.f, a1 = 0.f;
    const float* base = H + (size_t)lane * VEC;

#define GATHER(E) { int c_ = (E).x; float v_ = __int_as_float((E).y);              \
        if constexpr (VEC == 2) {                                                  \
            float2 h_ = *(const float2*)(base + (size_t)c_ * F);                   \
            a0 += v_ * h_.x; a1 += v_ * h_.y;                                      \
        } else {                                                                   \
            a0 += v_ * base[(size_t)c_ * F];                                       \
        } }

    int p = s;
    for (; p + 4 <= e; p += 4) {
        int2 e0 = edge[p], e1 = edge[p + 1], e2 = edge[p + 2], e3 = edge[p + 3];
        GATHER(e0) GATHER(e1) GATHER(e2) GATHER(e3)
    }
    for (; p < e; ++p) {
        int2 e0 = edge[p];
        GATHER(e0)
    }
#undef GATHER

    float* o = O + (size_t)w * F + (size_t)lane * VEC;
    if constexpr (VEC == 2) { o[0] = a0; o[1] = a1; }
    else                    { o[0] = a0; }
}

// ---------------- fp32 GEMM: Y[M,N] = X[M,128] @ W[N,128]^T ----------------

template<int N>   // N = 128 or 64
__global__ __launch_bounds__(256) void gemm_xwt(const float* __restrict__ X,
                                                const float* __restrict__ W,
                                                float* __restrict__ Y, int M) {
    constexpr int K = 128, BM = 64, BK = 32;
    constexpr int TM = 4, TN = N / 16;
    __shared__ float Xs[BK][BM + 4];    // padded, rows 16B-aligned
    __shared__ float Ws[BK][N + 4];
    int t  = threadIdx.x;
    int m0 = blockIdx.x * BM;
    int r0 = (t >> 4) * TM;
    int c0 = (t & 15) * TN;
    float acc[TM][TN] = {};
    for (int k0 = 0; k0 < K; k0 += BK) {
        #pragma unroll
        for (int i = 0; i < 2; ++i) {            // X tile: 512 float4
            int f  = t + i * 256;
            int m  = f >> 3;
            int kq = (f & 7) << 2;
            int gm = m0 + m; if (gm >= M) gm = M - 1;
            float4 v = *(const float4*)&X[(size_t)gm * K + k0 + kq];
            Xs[kq + 0][m] = v.x; Xs[kq + 1][m] = v.y;
            Xs[kq + 2][m] = v.z; Xs[kq + 3][m] = v.w;
        }
        #pragma unroll
        for (int i = 0; i < N / 32; ++i) {       // W tile: N*8 float4
            int f  = t + i * 256;
            int n  = f >> 3;
            int kq = (f & 7) << 2;
            float4 v = *(const float4*)&W[(size_t)n * K + k0 + kq];
            Ws[kq + 0][n] = v.x; Ws[kq + 1][n] = v.y;
            Ws[kq + 2][n] = v.z; Ws[kq + 3][n] = v.w;
        }
        __syncthreads();
        #pragma unroll
        for (int k = 0; k < BK; ++k) {
            float4 xv = *(const float4*)&Xs[k][r0];
            float xf[TM] = {xv.x, xv.y, xv.z, xv.w};
            float wf[TN];
            #pragma unroll
            for (int j = 0; j < TN; j += 4) {
                float4 wv = *(const float4*)&Ws[k][c0 + j];
                wf[j] = wv.x; wf[j + 1] = wv.y; wf[j + 2] = wv.z; wf[j + 3] = wv.w;
            }
            #pragma unroll
            for (int i = 0; i < TM; ++i)
                #pragma unroll
                for (int j = 0; j < TN; ++j)
                    acc[i][j] += xf[i] * wf[j];
        }
        __syncthreads();
    }
    #pragma unroll
    for (int i = 0; i < TM; ++i) {
        int gm = m0 + r0 + i;
        if (gm < M) {
            #pragma unroll
            for (int j = 0; j < TN; j += 4) {
                float4 v = {acc[i][j], acc[i][j + 1], acc[i][j + 2], acc[i][j + 3]};
                *(float4*)&Y[(size_t)gm * N + c0 + j] = v;
            }
        }
    }
}

// ---------------- launch ----------------

extern "C" void kernel_launch(void* const* d_in, const int* in_sizes, int n_in,
                              void* d_out, int out_size, void* d_ws, size_t ws_size,
                              hipStream_t stream) {
    const float* x     = (const float*)d_in[0];
    const void*  edges = d_in[1];
    const float* W1    = (const float*)d_in[2];
    const float* W2    = (const float*)d_in[3];
    float* out = (float*)d_out;

    char* ws = (char*)d_ws;
    size_t off = 0;
    auto take = [&](size_t bytes) -> char* {
        char* p = ws + off;
        off = (off + bytes + 255) & ~(size_t)255;
        return p;
    };
    int*   flag   = (int*)take(4);
    int*   e32    = (int*)take((size_t)2 * NE * 4);
    int*   cnt    = (int*)take((size_t)NN * 4);        // degree counts, then fill cursor
    float* dinv   = (float*)take((size_t)NN * 4);
    int*   rowoff = (int*)take((size_t)(NN + 1) * 4);
    int*   part   = (int*)take(1024 * 4);
    int2*  edgeA  = (int2*)take((size_t)ENT * 8);
    float* h      = (float*)take((size_t)NN * 128 * 4);
    float* y      = (float*)take((size_t)NN * 128 * 4);
    if (off > ws_size) return;   // workspace too small: fail cleanly

    // --- build normalized CSR (by dst) ---
    hipMemsetAsync(cnt, 0, (size_t)NN * 4, stream);
    probe_kernel<<<1, 64, 0, stream>>>((const unsigned*)edges, flag);
    convert_kernel<<<(2 * NE + 255) / 256, 256, 0, stream>>>(edges, flag, e32, cnt);
    dinv_kernel<<<(NN + 255) / 256, 256, 0, stream>>>(cnt, dinv);
    int nb = (NN + 1023) / 1024;   // 98
    scan_local<<<nb, 1024, 0, stream>>>(cnt, rowoff, part);
    scan_part<<<1, 128, 0, stream>>>(part, nb);
    scan_add<<<(NN + 255) / 256, 256, 0, stream>>>(rowoff, cnt, part);
    fill_kernel<<<(ENT + 255) / 256, 256, 0, stream>>>(e32, dinv, cnt, edgeA);

    // --- 3 layers: GEMM then propagate ---
    const int GB = (NN + 63) / 64;          // 1563
    const int PB = (NN * 64 + 255) / 256;   // 25000 (one wave per node)

    gemm_xwt<128><<<GB, 256, 0, stream>>>(x, W1, h, NN);
    spmm_kernel<2><<<PB, 256, 0, stream>>>(rowoff, edgeA, h, y);

    gemm_xwt<128><<<GB, 256, 0, stream>>>(y, W1, h, NN);
    spmm_kernel<2><<<PB, 256, 0, stream>>>(rowoff, edgeA, h, y);

    gemm_xwt<64><<<GB, 256, 0, stream>>>(y, W2, h, NN);
    spmm_kernel<1><<<PB, 256, 0, stream>>>(rowoff, edgeA, h, out);
}